// Round 10
// baseline (59.316 us; speedup 1.0000x reference)
//
#include <hip/hip_runtime.h>
#include <hip/hip_bf16.h>
#include <cstdint>
#include <cstddef>

#define NS 2560
#define NQ 8192
#define NC 512
#define DD 1600

typedef __bf16 bf16_t;
typedef __bf16 bf16x4 __attribute__((ext_vector_type(4)));
typedef __bf16 bf16x8 __attribute__((ext_vector_type(8)));
typedef float f32x4 __attribute__((ext_vector_type(4)));

// ---------------------------------------------------------------------------
// Kernel 1: class-mean prototypes (bf16) + ||p||^2 (fp32). One block per class.
// ---------------------------------------------------------------------------
__global__ __launch_bounds__(256) void proto_kernel(
    const float* __restrict__ sup, const int* __restrict__ lab,
    bf16_t* __restrict__ protos, float* __restrict__ p2)
{
    const int m   = blockIdx.x;
    const int tid = threadIdx.x;
    __shared__ int   idxs[32];
    __shared__ int   cnt;
    __shared__ float wsum[4];
    if (tid == 0) cnt = 0;
    __syncthreads();
    for (int i = tid; i < NS; i += 256) {
        if (lab[i] == m) {
            int p = atomicAdd(&cnt, 1);
            if (p < 32) idxs[p] = i;
        }
    }
    __syncthreads();
    int n = cnt < 32 ? cnt : 32;
    if (tid == 0 && n > 1) {                       // deterministic order
        for (int a = 1; a < n; ++a) {
            int key = idxs[a]; int b = a - 1;
            while (b >= 0 && idxs[b] > key) { idxs[b+1] = idxs[b]; --b; }
            idxs[b+1] = key;
        }
    }
    __syncthreads();

    float acc[7];
    #pragma unroll
    for (int u = 0; u < 7; ++u) acc[u] = 0.f;
    for (int t = 0; t < n; ++t) {
        const float* src = sup + (size_t)idxs[t] * DD;
        #pragma unroll
        for (int u = 0; u < 7; ++u) {
            int j = tid + u * 256;
            if (j < DD) acc[u] += src[j];
        }
    }
    float inv = (n > 0) ? 1.f / (float)n : 0.f;
    float psq = 0.f;
    #pragma unroll
    for (int u = 0; u < 7; ++u) {
        int j = tid + u * 256;
        if (j < DD) {
            float p = acc[u] * inv;
            bf16_t pb = (bf16_t)p;
            protos[(size_t)m * DD + j] = pb;
            float pf = (float)pb;
            psq += pf * pf;
        }
    }
    #pragma unroll
    for (int o = 32; o > 0; o >>= 1) psq += __shfl_xor(psq, o);
    int lane = tid & 63, wid = tid >> 6;
    if (lane == 0) wsum[wid] = psq;
    __syncthreads();
    if (tid == 0) p2[m] = wsum[0] + wsum[1] + wsum[2] + wsum[3];
}

// ---------------------------------------------------------------------------
// B staging: 128 cols x 64 K bf16 tile (16 KB) via global_load_lds, linear
// LDS dest + pre-swizzled global source. 1024 granules / 512 threads = 2 each.
// ---------------------------------------------------------------------------
__device__ __forceinline__ void stage_B(const bf16_t* __restrict__ pb,
                                        char* bbuf, int k0, int tid, int wid)
{
    #pragma unroll
    for (int p = 0; p < 2; ++p) {
        int idx  = p * 512 + tid;             // 16B granule index
        int row  = idx >> 3;                  // tile-local col 0..127
        int gcol = (idx & 7) ^ (row & 7);     // inverse swizzle on source
        const bf16_t* src = pb + (size_t)row * DD + k0 + gcol * 8;
        char* dst = bbuf + (size_t)(p * 512 + wid * 64) * 16;  // wave-uniform
        __builtin_amdgcn_global_load_lds(
            (const __attribute__((address_space(1))) void*)src,
            (__attribute__((address_space(3))) void*)dst, 16, 0, 0);
    }
}

// ---------------------------------------------------------------------------
// Kernel 2: GEMM -> logits. 128 query rows x 128 classes per block, 8 waves
// (2x4 wave grid, each wave a 64x32 sub-tile), grid (64,4) = 256 blocks.
// Round-9 falsified occupancy-as-lever; the real defect was compute
// intensity: 21 FLOP/staged-byte. This config: 16 MFMA/wave/iter over
// 48 KB staged = 64 FLOP/B (m97 level), and L2 inbound drops 630->315 MB.
// Double-buffered (2x16KB B, 2x16KB A), stage(t+1) issued BEFORE compute(t),
// one __syncthreads per iter (drain overlaps compute). XOR-swizzled LDS.
// Writes logits = 2*dot - |p|^2 into d_out; lsm pass normalizes in place.
// ---------------------------------------------------------------------------
__global__ __launch_bounds__(512, 2) void gemm_kernel(
    const float* __restrict__ q, const bf16_t* __restrict__ protos,
    const float* __restrict__ p2, float* __restrict__ out)
{
    extern __shared__ char smem[];
    // Bs0 @0, Bs1 @16384, As0 @32768, As1 @49152  (64 KB total)

    const int tid  = threadIdx.x;
    const int lane = tid & 63;
    const int wid  = tid >> 6;        // 0..7
    const int wm   = wid >> 2;        // wave row 0..1  (64 rows each)
    const int wn   = wid & 3;         // wave col 0..3  (32 cols each)
    const int r    = lane & 15;
    const int g    = lane >> 4;
    const int m0   = blockIdx.x * 128;
    const int n0   = blockIdx.y * 128;

    const bf16_t* pb = protos + (size_t)n0 * DD;

    float p2c[2];
    #pragma unroll
    for (int ni = 0; ni < 2; ++ni) p2c[ni] = p2[n0 + wn * 32 + ni * 16 + r];

    f32x4 acc[4][2];
    #pragma unroll
    for (int mi = 0; mi < 4; ++mi)
        #pragma unroll
        for (int ni = 0; ni < 2; ++ni)
            acc[mi][ni] = (f32x4){0.f, 0.f, 0.f, 0.f};

    // A staging coords: granule idx = u*512+tid (u<4); row = idx>>4, cg = tid&15
    const int acg = tid & 15;
    int          arow[4];
    const float* ap[4];
    int          ao[4];
    #pragma unroll
    for (int u = 0; u < 4; ++u) {
        arow[u] = (u * 512 + tid) >> 4;                 // 0..127
        ap[u]   = q + (size_t)(m0 + arow[u]) * DD + acg * 4;
        ao[u]   = (arow[u] * 128 + acg * 8) ^ ((arow[u] & 7) << 4);
    }

    // ---- prologue: stage tile 0 into buffer 0 ----
    {
        float4 f[4];
        #pragma unroll
        for (int u = 0; u < 4; ++u) f[u] = *(const float4*)(ap[u]);
        stage_B(pb, smem, 0, tid, wid);
        #pragma unroll
        for (int u = 0; u < 4; ++u) {
            bf16x4 w;
            w[0] = (bf16_t)f[u].x; w[1] = (bf16_t)f[u].y;
            w[2] = (bf16_t)f[u].z; w[3] = (bf16_t)f[u].w;
            *(bf16x4*)(smem + 32768 + ao[u]) = w;
        }
        __syncthreads();
    }

    for (int t = 0; t < 25; ++t) {
        const int cur = t & 1;
        const char* bs  = smem + cur * 16384;
        char*       bsn = smem + (cur ^ 1) * 16384;
        const char* as  = smem + 32768 + cur * 16384;
        char*       asn = smem + 32768 + (cur ^ 1) * 16384;
        const bool  pre = (t < 24);

        // ---- issue next tile: A fp32 loads first, then B gloads ----
        float4 fA[4];
        if (pre) {
            #pragma unroll
            for (int u = 0; u < 4; ++u)
                fA[u] = *(const float4*)(ap[u] + (t + 1) * 64);
            stage_B(pb, bsn, (t + 1) * 64, tid, wid);
        }

        // ---- compute current tile: 2 K-slices of 32, 16 MFMA ----
        #pragma unroll
        for (int kk = 0; kk < 2; ++kk) {
            bf16x8 af[4], bfr[2];
            #pragma unroll
            for (int mi = 0; mi < 4; ++mi) {
                int a_r = wm * 64 + mi * 16 + r;
                int ab  = (a_r * 128 + kk * 64 + g * 16) ^ ((a_r & 7) << 4);
                af[mi] = *(const bf16x8*)(as + ab);
            }
            #pragma unroll
            for (int ni = 0; ni < 2; ++ni) {
                int c  = wn * 32 + ni * 16 + r;    // LDS row (tile-local col)
                int bb = (c * 128 + kk * 64 + g * 16) ^ ((c & 7) << 4);
                bfr[ni] = *(const bf16x8*)(bs + bb);
            }
            #pragma unroll
            for (int mi = 0; mi < 4; ++mi)
                #pragma unroll
                for (int ni = 0; ni < 2; ++ni)
                    acc[mi][ni] = __builtin_amdgcn_mfma_f32_16x16x32_bf16(
                        af[mi], bfr[ni], acc[mi][ni], 0, 0, 0);
        }

        // ---- convert + write A(t+1) into other buffer ----
        if (pre) {
            #pragma unroll
            for (int u = 0; u < 4; ++u) {
                bf16x4 w;
                w[0] = (bf16_t)fA[u].x; w[1] = (bf16_t)fA[u].y;
                w[2] = (bf16_t)fA[u].z; w[3] = (bf16_t)fA[u].w;
                *(bf16x4*)(asn + ao[u]) = w;
            }
        }
        __syncthreads();   // drain completes next tile; LDS reads done
    }

    // ---- write logits = 2*dot - |p|^2 ----
    #pragma unroll
    for (int mi = 0; mi < 4; ++mi) {
        #pragma unroll
        for (int j = 0; j < 4; ++j) {
            size_t rowoff = (size_t)(m0 + wm * 64 + mi * 16 + g * 4 + j) * NC + n0;
            #pragma unroll
            for (int ni = 0; ni < 2; ++ni)
                out[rowoff + wn * 32 + ni * 16 + r] =
                    2.f * acc[mi][ni][j] - p2c[ni];
        }
    }
}

// ---------------------------------------------------------------------------
// Kernel 3: in-place row log_softmax on d_out. One wave per row.
// ---------------------------------------------------------------------------
__global__ __launch_bounds__(256) void lsm_kernel(float* __restrict__ io)
{
    const int row  = blockIdx.x * 4 + (threadIdx.x >> 6);
    const int lane = threadIdx.x & 63;
    float* p = io + (size_t)row * NC + lane * 8;

    float4 a = *(const float4*)(p);
    float4 b = *(const float4*)(p + 4);
    float v[8] = {a.x, a.y, a.z, a.w, b.x, b.y, b.z, b.w};

    float mx = v[0];
    #pragma unroll
    for (int i = 1; i < 8; ++i) mx = fmaxf(mx, v[i]);
    #pragma unroll
    for (int o = 32; o > 0; o >>= 1) mx = fmaxf(mx, __shfl_xor(mx, o));
    float se = 0.f;
    #pragma unroll
    for (int i = 0; i < 8; ++i) se += expf(v[i] - mx);
    #pragma unroll
    for (int o = 32; o > 0; o >>= 1) se += __shfl_xor(se, o);
    float lz = mx + logf(se);

    float4 o1 = {v[0]-lz, v[1]-lz, v[2]-lz, v[3]-lz};
    float4 o2 = {v[4]-lz, v[5]-lz, v[6]-lz, v[7]-lz};
    *(float4*)(p)     = o1;
    *(float4*)(p + 4) = o2;
}

// ---------------------------------------------------------------------------
extern "C" void kernel_launch(void* const* d_in, const int* in_sizes, int n_in,
                              void* d_out, int out_size, void* d_ws, size_t ws_size,
                              hipStream_t stream)
{
    const float* sup = (const float*)d_in[0];   // [2560,64,5,5]
    const float* qry = (const float*)d_in[1];   // [8192,64,5,5]
    const int*   lab = (const int*)d_in[2];     // [2560]
    float* out = (float*)d_out;                 // [8192,512]

    char* ws = (char*)d_ws;
    bf16_t* protos = (bf16_t*)ws;               // 512*1600*2 = 1,638,400 B
    float*  p2     = (float*)(ws + 1638400);    // 2 KB

    const int smem_bytes = 65536;               // 2x16KB B + 2x16KB A
    hipFuncSetAttribute(reinterpret_cast<const void*>(gemm_kernel),
                        hipFuncAttributeMaxDynamicSharedMemorySize, smem_bytes);

    proto_kernel<<<NC, 256, 0, stream>>>(sup, lab, protos, p2);
    gemm_kernel<<<dim3(NQ / 128, NC / 128), 512, smem_bytes, stream>>>(qry, protos, p2, out);
    lsm_kernel<<<NQ / 4, 256, 0, stream>>>(out);
}